// Round 9
// baseline (117.234 us; speedup 1.0000x reference)
//
#include <hip/hip_runtime.h>

// Problem constants
#define HDIM 64
#define LSEQ 2048
#define BATCH 16
#define LN_EPS 1e-5f
#define D_EPS 1e-6f
#define NSEG 32      // segments per batch (64 tokens per block)
#define CPS 4        // chunks per segment (16 tokens each)

typedef unsigned short u16;
typedef unsigned int   u32;
typedef __attribute__((ext_vector_type(8))) short bf16x8;  // 8 bf16 (4 VGPRs)
typedef __attribute__((ext_vector_type(4))) float f32x4;   // MFMA C/D frag

__device__ __forceinline__ float bf2f(u16 v) {
    return __uint_as_float(((u32)v) << 16);
}
__device__ __forceinline__ u16 f2bf(float f) {   // round-to-nearest-even
    u32 u = __float_as_uint(f);
    return (u16)((u + 0x7FFFu + ((u >> 16) & 1u)) >> 16);
}

// async global->LDS copy, 16B per lane (dest = wave-uniform base + lane*16)
#define GLOAD_LDS16(gp, lp) __builtin_amdgcn_global_load_lds( \
    (const __attribute__((address_space(1))) u32*)(gp),       \
    (__attribute__((address_space(3))) u32*)(lp), 16, 0, 0)

// ---------------- shared-memory overlay (bytes), total 76032 ----------------
// 2 blocks/CU: 2 x 76032 = 152064 <= 163840.
// Phase A scratch (dead after preprocess):
#define A_ER   0        // embeddings row-major f32 [64][68]   17408
#define A_HF   17408    // hidden relu, A-frag [w4][ks4][l][8] 16384 -> 33792
#define A_W1L  33792    // W1 frags staged via global_load_lds 16384 -> 50176
#define A_W2L  50176    // W2 frags staged via global_load_lds 16384 -> 66560
// Phase B scratch (overlays Phase A; ends 34368 — clobbers dead W1L head):
#define B_GM   0        // f32 [16][17] shared                 1088
#define B_BH   1088     // u16 [16][72] shared (B hi)          2304
#define B_BL   3392     // u16 [16][72] shared (B lo)          2304
#define B_SH   5696     // u16 4x[16][72] per-wave S^T hi      9216
#define B_SL   14912    // u16 4x[16][72] per-wave S^T lo      9216
#define B_ZN   24128    // u32 4x[16][20] per-wave -iv*Z       5120
#define B_ZV   29248    // u32 4x[16][20] per-wave  Z          5120 -> 34368
// Persistent across phases A/B:
#define H_T    66560    // bf16 [64][72]  h transposed (hT[o][token]) 9216
#define H_INVD 75776    // f32 [64]                            256
#define SMEM_BYTES 76032

// ---------------------------------------------------------------------------
// Kernel 0: one-shot weight frag conversion (f32 -> bf16, MFMA-B-frag order).
// Slot sIdx = frag*64 + lane; lane provides B[(lane>>4)*8+i][lane&15].
// ---------------------------------------------------------------------------
__global__ __launch_bounds__(256) void prep_w_kernel(
    const float* __restrict__ W1, const float* __restrict__ W2,
    u16* __restrict__ W1F, u16* __restrict__ W2F)
{
    const int sIdx = blockIdx.x * 256 + threadIdx.x;  // 0..2047
    const int s10  = sIdx & 1023;
    const int f    = s10 >> 6, l = s10 & 63;
    const int cc   = l & 15,  gg = l >> 4;
    u16 tmp[8];
    if (sIdx < 1024) {
        const int ks = f >> 3, nt = f & 7;
        const int o = nt * 16 + cc, k0 = ks * 32 + gg * 8;
#pragma unroll
        for (int i = 0; i < 8; ++i) tmp[i] = f2bf(W1[(k0 + i) * 128 + o]);
        *(ushort4*)&W1F[s10 * 8]     = *(ushort4*)&tmp[0];
        *(ushort4*)&W1F[s10 * 8 + 4] = *(ushort4*)&tmp[4];
    } else {
        const int ks = f >> 2, nt = f & 3;
        const int o = nt * 16 + cc, k0 = ks * 32 + gg * 8;
#pragma unroll
        for (int i = 0; i < 8; ++i) tmp[i] = f2bf(W2[(k0 + i) * 64 + o]);
        *(ushort4*)&W2F[s10 * 8]     = *(ushort4*)&tmp[0];
        *(ushort4*)&W2F[s10 * 8 + 4] = *(ushort4*)&tmp[4];
    }
}

// ---------------------------------------------------------------------------
// Kernel A: fused preprocess + segment composition. 512 blocks @ 2/CU.
// R17: Phase A MLPs on MFMA. R18: Phase B on MFMA (split-bf16 f32-grade).
// R19: pre-fragged weights; de-dup'd lockstep Phase B; hT vector reads.
// R20/R22 LESSON (twice-confirmed): in-kernel cross-XCD sync costs 60-100us;
//   the kernel LAUNCH BOUNDARY is the cheap global release. Keep 3 launches.
// R21 LESSON: reg-prefetching weight frags (+128 VGPR) regressed — but that
//   test confounded mechanism (hide W-load L2 latency) with implementation
//   (VGPR pressure).
// R23: hT-only h store; vectorized LN epilogue (neutral — kept for clarity).
// R24: W1F/W2F staged to LDS via global_load_lds (async DMA, zero VGPR cost)
//   at kernel entry; the staging __syncthreads drains vmcnt. W1F layout is
//   already frag-major lane-linear = the required wave-uniform-base+lane*16
//   dest pattern. MFMA operand loads become ds_read_b128 (conflict-free).
// Fragment maps (HW-verified, learn_hip m89/m91/m92):
//   A: lane holds A[lane&15][(lane>>4)*8 + i], i=0..7
//   B: lane holds B[(lane>>4)*8 + i][lane&15]
//   C/D: col = lane&15, row = (lane>>4)*4 + reg
// ---------------------------------------------------------------------------
__global__ __launch_bounds__(256, 2) void fused_pc_kernel(
    const int* __restrict__ seq, const float* __restrict__ embed,
    const u16* __restrict__ W1F, const float* __restrict__ b1,
    const u16* __restrict__ W2F, const float* __restrict__ b2,
    const float* __restrict__ gamma, const float* __restrict__ beta,
    u32* __restrict__ PK, u16* __restrict__ q_ws)
{
    __shared__ __align__(16) char smem[SMEM_BYTES];
    const int t = threadIdx.x;
    const int b = blockIdx.x >> 5;
    const int s = blockIdx.x & 31;
    const int tok0 = 1984 - 64 * s;           // first token of this block

    u16*   hT     = (u16*)(smem + H_T);
    float* invd_l = (float*)(smem + H_INVD);

    const int lane = t & 63;
    const int w    = t >> 6;      // wave id
    const int g    = lane >> 4;   // k-group / row-group
    const int c    = lane & 15;   // column within tile

    // ======================= Phase A: preprocess ==========================
    {
        float* eR  = (float*)(smem + A_ER);
        u16*   hF  = (u16*)(smem + A_HF);
        u16*   W1L = (u16*)(smem + A_W1L);
        u16*   W2L = (u16*)(smem + A_W2L);

        // R24: async-stage all 32 weight frags to LDS (wave w: frags 4w..4w+3
        // of each; one issue = 64 lanes x 16B = one 1024B frag). Latency
        // hides under seq/embed staging; the barrier below drains vmcnt.
#pragma unroll
        for (int q = 0; q < 4; ++q) {
            const int f = w * 4 + q;
            GLOAD_LDS16(&W1F[(f * 64 + lane) * 8], &W1L[f * 512]);
            GLOAD_LDS16(&W2F[(f * 64 + lane) * 8], &W2L[f * 512]);
        }

        // stage embeddings row-major f32 (coalesced float4 writes)
        {
            const int tk = t >> 2, p = t & 3;
            const int v = seq[b * LSEQ + tok0 + tk];
            const float* er = embed + v * HDIM + 16 * p;
#pragma unroll
            for (int q = 0; q < 4; ++q)
                *(float4*)&eR[tk * 68 + 16 * p + 4 * q] = *(const float4*)(er + 4 * q);
        }
        __syncthreads();

        // A-frags of e: lane holds e[16w + c][ks*32 + g*8 .. +7], bf16 RNE
        bf16x8 ea[2];
#pragma unroll
        for (int ks = 0; ks < 2; ++ks) {
            const float* src = &eR[(16 * w + c) * 68 + ks * 32 + g * 8];
            const float4 v0 = *(const float4*)src;
            const float4 v1 = *(const float4*)(src + 4);
            bf16x8 f;
            f[0] = (short)f2bf(v0.x); f[1] = (short)f2bf(v0.y);
            f[2] = (short)f2bf(v0.z); f[3] = (short)f2bf(v0.w);
            f[4] = (short)f2bf(v1.x); f[5] = (short)f2bf(v1.y);
            f[6] = (short)f2bf(v1.z); f[7] = (short)f2bf(v1.w);
            ea[ks] = f;
        }

        // MLP1: hid = relu(e W1 + b1) -> hF in A-frag layout (same-wave RAW).
#pragma unroll
        for (int nt = 0; nt < 8; ++nt) {
            const float bv = b1[16 * nt + c];
            f32x4 acc = {bv, bv, bv, bv};
#pragma unroll
            for (int ks = 0; ks < 2; ++ks) {
                const bf16x8 bf = *(const bf16x8*)&W1L[((ks * 8 + nt) * 64 + lane) * 8];
                acc = __builtin_amdgcn_mfma_f32_16x16x32_bf16(ea[ks], bf, acc, 0, 0, 0);
            }
            const int o   = 16 * nt + c;          // k2 index for MLP2
            const int ks2 = o >> 5;
            const int l4  = ((o >> 3) & 3) << 4;
            const int i   = o & 7;
#pragma unroll
            for (int r = 0; r < 4; ++r) {
                const float hv = fmaxf(acc[r], 0.f);
                hF[((w * 4 + ks2) * 64 + l4 + g * 4 + r) * 8 + i] = f2bf(hv);
            }
        }

        // MLP2: x = hid W2 + b2 + e
        bf16x8 ha[4];
#pragma unroll
        for (int ks = 0; ks < 4; ++ks)
            ha[ks] = *(const bf16x8*)&hF[((w * 4 + ks) * 64 + lane) * 8];

        float xf[4][4];   // [nt][r]
#pragma unroll
        for (int nt = 0; nt < 4; ++nt) {
            const float bv = b2[16 * nt + c];
            f32x4 acc = {bv, bv, bv, bv};
#pragma unroll
            for (int ks = 0; ks < 4; ++ks) {
                const bf16x8 bf = *(const bf16x8*)&W2L[((ks * 4 + nt) * 64 + lane) * 8];
                acc = __builtin_amdgcn_mfma_f32_16x16x32_bf16(ha[ks], bf, acc, 0, 0, 0);
            }
#pragma unroll
            for (int r = 0; r < 4; ++r)
                xf[nt][r] = acc[r] + eR[(16 * w + g * 4 + r) * 68 + 16 * nt + c];
        }

        // LayerNorm in registers over the 16 lanes sharing g
        float s4[4] = {0, 0, 0, 0}, q4[4] = {0, 0, 0, 0};
#pragma unroll
        for (int nt = 0; nt < 4; ++nt)
#pragma unroll
            for (int r = 0; r < 4; ++r) {
                s4[r] += xf[nt][r];
                q4[r] = fmaf(xf[nt][r], xf[nt][r], q4[r]);
            }
#pragma unroll
        for (int m = 1; m < 16; m <<= 1)
#pragma unroll
            for (int r = 0; r < 4; ++r) {
                s4[r] += __shfl_xor(s4[r], m);
                q4[r] += __shfl_xor(q4[r], m);
            }
        float mu[4], rstd[4];
#pragma unroll
        for (int r = 0; r < 4; ++r) {
            mu[r] = s4[r] * (1.0f / 64.0f);
            const float var = q4[r] * (1.0f / 64.0f) - mu[r] * mu[r];
            rstd[r] = 1.0f / sqrtf(var + LN_EPS);
        }

        // normalize, bf16-round; hh over ROUNDED values; pack 4 rows ->
        // one ds_write_b64 per nt into hT.
        float hh[4] = {0, 0, 0, 0};
#pragma unroll
        for (int nt = 0; nt < 4; ++nt) {
            const int o = 16 * nt + c;
            const float gm = gamma[o], bt = beta[o];
            ushort4 pk4;
            u16* pp = (u16*)&pk4;
#pragma unroll
            for (int r = 0; r < 4; ++r) {
                const float ov = (xf[nt][r] - mu[r]) * rstd[r] * gm + bt;
                const u16 rb = f2bf(ov);
                const float qf = bf2f(rb);
                hh[r] = fmaf(qf, qf, hh[r]);
                u16 st = rb;
                if (s == 0 && w == 3 && g == 3 && r == 3) {  // token 2047
                    q_ws[b * 64 + o] = rb;   // export q
                    st = 0;                   // padded key sigma=0
                }
                pp[r] = st;
            }
            *(ushort4*)&hT[o * 72 + 16 * w + 4 * g] = pk4;
        }
#pragma unroll
        for (int m = 1; m < 16; m <<= 1)
#pragma unroll
            for (int r = 0; r < 4; ++r) hh[r] += __shfl_xor(hh[r], m);
        if (c == 0) {
#pragma unroll
            for (int r = 0; r < 4; ++r)
                invd_l[16 * w + g * 4 + r] = 1.0f / (hh[r] + D_EPS);
        }
    }
    __syncthreads();   // hT/invd finalized

    // ======================= Phase B: compose (MFMA, lockstep) ============
    {
        float* Gm = (float*)(smem + B_GM);              // shared (wave0-written)
        u16*   Bh = (u16*)(smem + B_BH);                // shared
        u16*   Bl = (u16*)(smem + B_BL);                // shared
        u16*   Sh = (u16*)(smem + B_SH) + w * 1152;     // per-wave S^T hi
        u16*   Sl = (u16*)(smem + B_SL) + w * 1152;     // per-wave S^T lo
        u32*   Zn = (u32*)(smem + B_ZN) + w * 320;      // per-wave
        u32*   Zv = (u32*)(smem + B_ZV) + w * 320;

        // init: S = I (wave w's column block), V = 0; S^T split to LDS
        f32x4 Sacc[4], Vacc[4];
#pragma unroll
        for (int mt = 0; mt < 4; ++mt) {
            ushort4 h4, l4;
            u16* hp = (u16*)&h4;
#pragma unroll
            for (int r = 0; r < 4; ++r) {
                const int m = 16 * mt + 4 * g + r;
                const float v = (m == 16 * w + c) ? 1.0f : 0.0f;
                Sacc[mt][r] = v;
                Vacc[mt][r] = 0.f;
                hp[r] = f2bf(v);
            }
            l4.x = 0; l4.y = 0; l4.z = 0; l4.w = 0;
            *(ushort4*)&Sh[c * 72 + 16 * mt + 4 * g] = h4;
            *(ushort4*)&Sl[c * 72 + 16 * mt + 4 * g] = l4;
        }

        // prologue: wave0 computes Gram for chunk 0 (hT read-only, strided)
        if (w == 0) {
            const int basep = 63;
            bf16x8 ka[2];
#pragma unroll
            for (int f = 0; f < 2; ++f) {
                bf16x8 kf;
#pragma unroll
                for (int i = 0; i < 8; ++i)
                    kf[i] = (short)hT[(f * 32 + g * 8 + i) * 72 + (basep - c)];
                ka[f] = kf;
            }
            f32x4 gacc = {0.f, 0.f, 0.f, 0.f};
            gacc = __builtin_amdgcn_mfma_f32_16x16x32_bf16(ka[0], ka[0], gacc, 0, 0, 0);
            gacc = __builtin_amdgcn_mfma_f32_16x16x32_bf16(ka[1], ka[1], gacc, 0, 0, 0);
            const float ivc = invd_l[basep - c];
#pragma unroll
            for (int r = 0; r < 4; ++r)
                Gm[(4 * g + r) * 17 + c] = gacc[r] * ivc;
        }

        for (int cc = 0; cc < CPS; ++cc) {
            const int base = 63 - 16 * cc;
            __syncthreads();   // B_a: Gm(cc) visible; prev-chunk Bh reads done

            // ---- fwd-sub, distributed: wave w handles columns 16w+c ----
            if (g == 0) {
                const int m = 16 * w + c;
                const u16* hp = &hT[m * 72 + base - 15];
                const ushort4 k0 = *(const ushort4*)&hp[0];
                const ushort4 k1 = *(const ushort4*)&hp[4];
                const ushort4 k2 = *(const ushort4*)&hp[8];
                const ushort4 k3 = *(const ushort4*)&hp[12];
                const u16 kv[16] = {k0.x, k0.y, k0.z, k0.w, k1.x, k1.y, k1.z, k1.w,
                                    k2.x, k2.y, k2.z, k2.w, k3.x, k3.y, k3.z, k3.w};
                float Breg[16];
#pragma unroll
                for (int i = 0; i < 16; ++i) {
                    float acc = bf2f(kv[15 - i]);   // hT idx j -> slot i=15-j
#pragma unroll
                    for (int j = 0; j < 16; ++j)
                        if (j < i) acc = fmaf(-Gm[i * 17 + j], Breg[j], acc);
                    Breg[i] = acc;
                }
#pragma unroll
                for (int i = 0; i < 16; ++i) {
                    const u16 hb = f2bf(Breg[i]);
                    Bh[i * 72 + m] = hb;
                    Bl[i * 72 + m] = f2bf(Breg[i] - bf2f(hb));
                }
            }
            __syncthreads();   // B_b: Bh/Bl visible

            // ---- Z = B * S (split-bf16, 6 MFMAs; own column block) ----
            const bf16x8 abh0 = *(const bf16x8*)&Bh[c * 72 +  0 + g * 8];
            const bf16x8 abh1 = *(const bf16x8*)&Bh[c * 72 + 32 + g * 8];
            const bf16x8 abl0 = *(const bf16x8*)&Bl[c * 72 +  0 + g * 8];
            const bf16x8 abl1 = *(const bf16x8*)&Bl[c * 72 + 32 + g * 8];
            const bf16x8 sh0  = *(const bf16x8*)&Sh[c * 72 +  0 + g * 8];
            const bf16x8 sh1  = *(const bf16x8*)&Sh[c * 72 + 32 + g * 8];
            const bf16x8 sl0  = *(const bf16x8*)&Sl[c * 72 +  0 + g * 8];
            const bf16x8 sl1  = *(const bf16x8*)&Sl[c * 72 + 32 + g * 8];
            f32x4 zacc = {0.f, 0.f, 0.f, 0.f};
            zacc = __builtin_amdgcn_mfma_f32_16x16x32_bf16(abh0, sh0, zacc, 0, 0, 0);
            zacc = __builtin_amdgcn_mfma_f32_16x16x32_bf16(abh1, sh1, zacc, 0, 0, 0);
            zacc = __builtin_amdgcn_mfma_f32_16x16x32_bf16(abh0, sl0, zacc, 0, 0, 0);
            zacc = __builtin_amdgcn_mfma_f32_16x16x32_bf16(abh1, sl1, zacc, 0, 0, 0);
            zacc = __builtin_amdgcn_mfma_f32_16x16x32_bf16(abl0, sh0, zacc, 0, 0, 0);
            zacc = __builtin_amdgcn_mfma_f32_16x16x32_bf16(abl1, sh1, zacc, 0, 0, 0);

            // ---- scale by invd, split, pack (hi<<16)|lo ----
            uint4 znp, zvp;
            u32* znpp = (u32*)&znp;
            u32* zvpp = (u32*)&zvp;
#pragma unroll
            for (int r = 0; r < 4; ++r) {
                const int j = 4 * g + r;
                const float iv = invd_l[base - j];
                const float z  = zacc[r];
                const float zt = -z * iv;
                const u16 nh = f2bf(zt);
                const u16 nl = f2bf(zt - bf2f(nh));
                znpp[r] = ((u32)nh << 16) | (u32)nl;
                const u16 vh = f2bf(z);
                const u16 vl = f2bf(z - bf2f(vh));
                zvpp[r] = ((u32)vh << 16) | (u32)vl;
            }
            *(uint4*)&Zn[c * 20 + 4 * g] = znp;
            *(uint4*)&Zv[c * 20 + 4 * g] = zvp;

            // ---- read back as B-frags (rows j0..j0+7; hi for g<2, lo else) ----
            const int j0 = (g & 1) * 8;
            const uint4 za0 = *(const uint4*)&Zn[c * 20 + j0];
            const uint4 za1 = *(const uint4*)&Zn[c * 20 + j0 + 4];
            const uint4 zb0 = *(const uint4*)&Zv[c * 20 + j0];
            const uint4 zb1 = *(const uint4*)&Zv[c * 20 + j0 + 4];
            bf16x8 znf, zvf;
            {
                const u32 zn8[8] = {za0.x, za0.y, za0.z, za0.w, za1.x, za1.y, za1.z, za1.w};
                const u32 zv8[8] = {zb0.x, zb0.y, zb0.z, zb0.w, zb1.x, zb1.y, zb1.z, zb1.w};
                const bool hi = (g < 2);
#pragma unroll
                for (int i8 = 0; i8 < 8; ++i8) {
                    znf[i8] = (short)(hi ? (zn8[i8] >> 16) : (zn8[i8] & 0xFFFFu));
                    zvf[i8] = (short)(hi ? (zv8[i8] >> 16) : (zv8[i8] & 0xFFFFu));
                }
            }

            // ---- S/V update: A-frag K^T via vector hT reads ----
#pragma unroll
            for (int mt = 0; mt < 4; ++mt) {
                const u16* kp = &hT[(16 * mt + c) * 72 + base - j0 - 7];
                const ushort4 ta = *(const ushort4*)&kp[0];
                const ushort4 tb = *(const ushort4*)&kp[4];
                const u16 kvv[8] = {ta.x, ta.y, ta.z, ta.w, tb.x, tb.y, tb.z, tb.w};
                bf16x8 kaf;
#pragma unroll
                for (int i8 = 0; i8 < 8; ++i8)
                    kaf[i8] = (short)kvv[7 - i8];   // hT idx j -> i8 = 7-j
                Sacc[mt] = __builtin_amdgcn_mfma_f32_16x16x32_bf16(kaf, znf, Sacc[mt], 0, 0, 0);
                Vacc[mt] = __builtin_amdgcn_mfma_f32_16x16x32_bf16(kaf, zvf, Vacc[mt], 0, 0, 0);
            }
            // refresh S^T split in LDS for next chunk (same-wave only)
            if (cc < CPS - 1) {
#pragma unroll
                for (int mt = 0; mt < 4; ++mt) {
                    ushort4 h4, l4;
                    u16* hp = (u16*)&h4;
                    u16* lp = (u16*)&l4;
#pragma unroll
                    for (int r = 0; r < 4; ++r) {
                        const float sv = Sacc[mt][r];
                        const u16 hb = f2bf(sv);
                        hp[r] = hb;
                        lp[r] = f2bf(sv - bf2f(hb));
                    }
                    *(ushort4*)&Sh[c * 72 + 16 * mt + 4 * g] = h4;
                    *(ushort4*)&Sl[c * 72 + 16 * mt + 4 * g] = l4;
                }
            }
            // ---- pipeline: wave0 computes Gram for chunk cc+1 (from hT) ----
            if (w == 0 && cc + 1 < CPS) {
                const int basep = base - 16;
                bf16x8 ka[2];
#pragma unroll
                for (int f = 0; f < 2; ++f) {
                    bf16x8 kf;
#pragma unroll
                    for (int i = 0; i < 8; ++i)
                        kf[i] = (short)hT[(f * 32 + g * 8 + i) * 72 + (basep - c)];
                    ka[f] = kf;
                }
                f32x4 gacc = {0.f, 0.f, 0.f, 0.f};
                gacc = __builtin_amdgcn_mfma_f32_16x16x32_bf16(ka[0], ka[0], gacc, 0, 0, 0);
                gacc = __builtin_amdgcn_mfma_f32_16x16x32_bf16(ka[1], ka[1], gacc, 0, 0, 0);
                const float ivc = invd_l[basep - c];
#pragma unroll
                for (int r = 0; r < 4; ++r)
                    Gm[(4 * g + r) * 17 + c] = gacc[r] * ivc;
            }
        }

        // writeback: pk[j*64+i] = pack(bf16 S[i][j], bf16 V[i][j])
        u32* pk = PK + ((size_t)(b * NSEG + s) << 12);
#pragma unroll
        for (int mt = 0; mt < 4; ++mt) {
            uint4 o;
            u32* op = (u32*)&o;
#pragma unroll
            for (int r = 0; r < 4; ++r)
                op[r] = ((u32)f2bf(Sacc[mt][r]) << 16) | (u32)f2bf(Vacc[mt][r]);
            *(uint4*)&pk[(16 * w + c) * 64 + 16 * mt + 4 * g] = o;
        }
    }
}

// ---------------------------------------------------------------------------
// Kernel B: serial segment pass + output projection (R4-exact).
// ---------------------------------------------------------------------------
__global__ __launch_bounds__(256, 1) void final_kernel(
    const u16* __restrict__ q_ws, const u32* __restrict__ PK,
    const float* __restrict__ Wr, const float* __restrict__ br,
    const float* __restrict__ Wo, const float* __restrict__ bo,
    float* __restrict__ out)
{
    const int b    = blockIdx.x;
    const int t    = threadIdx.x;
    const int lane = t & 63;
    const int p    = t >> 6;         // wave id = j-slice

    __shared__ float psum[4][72];
    __shared__ float rl[64];
    __shared__ float cs[64], rs[64];

    rl[lane] = bf2f(q_ws[b * 64 + lane]);

    float ctxp = 0.f;
    u32 cur[16], nxt[16];
    {
        const u32* pk0 = PK + ((size_t)(b * NSEG + 0) << 12);
#pragma unroll
        for (int jj = 0; jj < 16; ++jj)
            cur[jj] = pk0[(p * 16 + jj) * 64 + lane];
    }
    __syncthreads();

    for (int s = 0; s < NSEG; ++s) {
        const int sn = (s + 1 < NSEG) ? s + 1 : s;
        const u32* pkn = PK + ((size_t)(b * NSEG + sn) << 12);
#pragma unroll
        for (int jj = 0; jj < 16; ++jj)
            nxt[jj] = pkn[(p * 16 + jj) * 64 + lane];

        float accr = 0.f;
#pragma unroll
        for (int jj = 0; jj < 16; ++jj) {
            const u32 pv = cur[jj];
            const float Sv = __uint_as_float(pv & 0xFFFF0000u);
            const float Vv = __uint_as_float(pv << 16);
            const float rj = rl[p * 16 + jj];
            accr = fmaf(Sv, rj, accr);
            ctxp = fmaf(Vv, rj, ctxp);
        }
        psum[p][lane] = accr;
        __syncthreads();
        const float rn = (psum[0][lane] + psum[1][lane]) + (psum[2][lane] + psum[3][lane]);
        __syncthreads();
        rl[lane] = rn;

#pragma unroll
        for (int jj = 0; jj < 16; ++jj) cur[jj] = nxt[jj];
    }

    psum[p][lane] = ctxp;
    __syncthreads();
    if (t < 64)
        cs[t] = (psum[0][t] + psum[1][t]) + (psum[2][t] + psum[3][t]);
    __syncthreads();

    float rv = (p == 0) ? br[lane] : 0.f;
#pragma unroll
    for (int i = 0; i < 16; ++i)
        rv = fmaf(cs[p * 16 + i], Wr[(p * 16 + i) * HDIM + lane], rv);
    psum[p][lane] = rv;
    __syncthreads();
    if (t < 64)
        rs[t] = (psum[0][t] + psum[1][t]) + (psum[2][t] + psum[3][t]);
    __syncthreads();

    float ov = (p == 0) ? bo[lane] : 0.f;
#pragma unroll
    for (int i = 0; i < 16; ++i)
        ov = fmaf(rs[p * 16 + i], Wo[(p * 16 + i) * HDIM + lane], ov);
    psum[p][lane] = ov;
    __syncthreads();
    if (t < 64)
        out[(size_t)b * HDIM + t] = (psum[0][t] + psum[1][t]) + (psum[2][t] + psum[3][t]);
}

// ---------------------------------------------------------------------------
extern "C" void kernel_launch(void* const* d_in, const int* in_sizes, int n_in,
                              void* d_out, int out_size, void* d_ws, size_t ws_size,
                              hipStream_t stream)
{
    const int*   seq   = (const int*)  d_in[0];
    const float* embed = (const float*)d_in[1];
    const float* W1    = (const float*)d_in[2];
    const float* b1    = (const float*)d_in[3];
    const float* W2    = (const float*)d_in[4];
    const float* b2    = (const float*)d_in[5];
    const float* gamma = (const float*)d_in[6];
    const float* beta  = (const float*)d_in[7];
    const float* Wr    = (const float*)d_in[8];
    const float* br    = (const float*)d_in[9];
    const float* Wo    = (const float*)d_in[10];
    const float* bo    = (const float*)d_in[11];

    u32* pk_ws = (u32*)d_ws;                                  // 8 MB (16*32*4096 u32)
    u16* q_ws  = (u16*)(pk_ws + (size_t)BATCH * NSEG * 4096); // 2 KB
    u16* W1F   = q_ws + (size_t)BATCH * 64;                   // 16 KB (8192 bf16)
    u16* W2F   = W1F + 64 * 128;                              // 16 KB
    float* outp = (float*)d_out;

    hipLaunchKernelGGL(prep_w_kernel, dim3(8), dim3(256), 0, stream,
                       W1, W2, W1F, W2F);
    hipLaunchKernelGGL(fused_pc_kernel, dim3(BATCH * NSEG), dim3(256), 0, stream,
                       seq, embed, W1F, b1, W2F, b2, gamma, beta, pk_ws, q_ws);
    hipLaunchKernelGGL(final_kernel, dim3(BATCH), dim3(256), 0, stream,
                       q_ws, pk_ws, Wr, br, Wo, bo, outp);
}

// Round 10
// 114.051 us; speedup vs baseline: 1.0279x; 1.0279x over previous
//
#include <hip/hip_runtime.h>

// Problem constants
#define HDIM 64
#define LSEQ 2048
#define BATCH 16
#define LN_EPS 1e-5f
#define D_EPS 1e-6f
#define NSEG 32      // segments per batch (64 tokens per block)
#define CPS 4        // chunks per segment (16 tokens each)

typedef unsigned short u16;
typedef unsigned int   u32;
typedef __attribute__((ext_vector_type(8))) short bf16x8;  // 8 bf16 (4 VGPRs)
typedef __attribute__((ext_vector_type(4))) float f32x4;   // MFMA C/D frag

__device__ __forceinline__ float bf2f(u16 v) {
    return __uint_as_float(((u32)v) << 16);
}
__device__ __forceinline__ u16 f2bf(float f) {   // round-to-nearest-even
    u32 u = __float_as_uint(f);
    return (u16)((u + 0x7FFFu + ((u >> 16) & 1u)) >> 16);
}

// ---------------- shared-memory overlay (bytes), total 52544 ----------------
// 2 blocks/CU: 2 x 52544 = 105088 <= 163840.
// Phase A scratch (dead after preprocess):
#define A_ER   0        // embeddings row-major f32 [64][68]   17408
#define A_HF   17408    // hidden relu, A-frag [w4][ks4][l][8] 16384 -> 33792
// Phase B scratch (overlays Phase A, all < 34368):
#define B_GM   0        // f32 [16][17] shared                 1088
#define B_BH   1088     // u16 [16][72] shared (B hi)          2304
#define B_BL   3392     // u16 [16][72] shared (B lo)          2304
#define B_SH   5696     // u16 4x[16][72] per-wave S^T hi      9216
#define B_SL   14912    // u16 4x[16][72] per-wave S^T lo      9216
#define B_ZN   24128    // u32 4x[16][20] per-wave -iv*Z       5120
#define B_ZV   29248    // u32 4x[16][20] per-wave  Z          5120 -> 34368
// Persistent across phases A/B (hrows deleted — hT is the only h store):
#define H_T    43072    // bf16 [64][72]  h transposed (hT[o][token]) 9216
#define H_INVD 52288    // f32 [64]                            256
#define SMEM_BYTES 52544

// ---------------------------------------------------------------------------
// Kernel 0: one-shot weight frag conversion (f32 -> bf16, MFMA-B-frag order).
// Slot sIdx = frag*64 + lane; lane provides B[(lane>>4)*8+i][lane&15].
// ---------------------------------------------------------------------------
__global__ __launch_bounds__(256) void prep_w_kernel(
    const float* __restrict__ W1, const float* __restrict__ W2,
    u16* __restrict__ W1F, u16* __restrict__ W2F)
{
    const int sIdx = blockIdx.x * 256 + threadIdx.x;  // 0..2047
    const int s10  = sIdx & 1023;
    const int f    = s10 >> 6, l = s10 & 63;
    const int cc   = l & 15,  gg = l >> 4;
    u16 tmp[8];
    if (sIdx < 1024) {
        const int ks = f >> 3, nt = f & 7;
        const int o = nt * 16 + cc, k0 = ks * 32 + gg * 8;
#pragma unroll
        for (int i = 0; i < 8; ++i) tmp[i] = f2bf(W1[(k0 + i) * 128 + o]);
        *(ushort4*)&W1F[s10 * 8]     = *(ushort4*)&tmp[0];
        *(ushort4*)&W1F[s10 * 8 + 4] = *(ushort4*)&tmp[4];
    } else {
        const int ks = f >> 2, nt = f & 3;
        const int o = nt * 16 + cc, k0 = ks * 32 + gg * 8;
#pragma unroll
        for (int i = 0; i < 8; ++i) tmp[i] = f2bf(W2[(k0 + i) * 64 + o]);
        *(ushort4*)&W2F[s10 * 8]     = *(ushort4*)&tmp[0];
        *(ushort4*)&W2F[s10 * 8 + 4] = *(ushort4*)&tmp[4];
    }
}

// ---------------------------------------------------------------------------
// Kernel A: fused preprocess + segment composition. 512 blocks @ 2/CU.
// FINAL (R25 = R23 revert): best verified structure, 114.06-114.47 us.
// R17: Phase A MLPs on MFMA. R18: Phase B on MFMA (split-bf16 f32-grade).
// R19: pre-fragged weights; de-dup'd lockstep Phase B; hT vector reads.
// Disproven levers (keep for posterity):
//   R20/R22: in-kernel cross-XCD sync (coop grid.sync / threadfence+flag
//     polling) costs 60-100us — device-scope release forces per-block L2
//     writeback on gfx950. The kernel launch boundary IS the cheap release.
//   R21/R24: hiding W-frag load latency (reg-prefetch +3us; global_load_lds
//     staging +2.7us) — demand loads interleaved per-wave are already best.
//   R23 epilogue vectorization: neutral (kept; not critical path).
// Fragment maps (HW-verified, learn_hip m89/m91/m92):
//   A: lane holds A[lane&15][(lane>>4)*8 + i], i=0..7
//   B: lane holds B[(lane>>4)*8 + i][lane&15]
//   C/D: col = lane&15, row = (lane>>4)*4 + reg
// ---------------------------------------------------------------------------
__global__ __launch_bounds__(256, 2) void fused_pc_kernel(
    const int* __restrict__ seq, const float* __restrict__ embed,
    const u16* __restrict__ W1F, const float* __restrict__ b1,
    const u16* __restrict__ W2F, const float* __restrict__ b2,
    const float* __restrict__ gamma, const float* __restrict__ beta,
    u32* __restrict__ PK, u16* __restrict__ q_ws)
{
    __shared__ __align__(16) char smem[SMEM_BYTES];
    const int t = threadIdx.x;
    const int b = blockIdx.x >> 5;
    const int s = blockIdx.x & 31;
    const int tok0 = 1984 - 64 * s;           // first token of this block

    u16*   hT     = (u16*)(smem + H_T);
    float* invd_l = (float*)(smem + H_INVD);

    const int lane = t & 63;
    const int w    = t >> 6;      // wave id
    const int g    = lane >> 4;   // k-group / row-group
    const int c    = lane & 15;   // column within tile

    // ======================= Phase A: preprocess ==========================
    {
        float* eR = (float*)(smem + A_ER);
        u16*   hF = (u16*)(smem + A_HF);

        // stage embeddings row-major f32 (coalesced float4 writes)
        {
            const int tk = t >> 2, p = t & 3;
            const int v = seq[b * LSEQ + tok0 + tk];
            const float* er = embed + v * HDIM + 16 * p;
#pragma unroll
            for (int q = 0; q < 4; ++q)
                *(float4*)&eR[tk * 68 + 16 * p + 4 * q] = *(const float4*)(er + 4 * q);
        }
        __syncthreads();

        // A-frags of e: lane holds e[16w + c][ks*32 + g*8 .. +7], bf16 RNE
        bf16x8 ea[2];
#pragma unroll
        for (int ks = 0; ks < 2; ++ks) {
            const float* src = &eR[(16 * w + c) * 68 + ks * 32 + g * 8];
            const float4 v0 = *(const float4*)src;
            const float4 v1 = *(const float4*)(src + 4);
            bf16x8 f;
            f[0] = (short)f2bf(v0.x); f[1] = (short)f2bf(v0.y);
            f[2] = (short)f2bf(v0.z); f[3] = (short)f2bf(v0.w);
            f[4] = (short)f2bf(v1.x); f[5] = (short)f2bf(v1.y);
            f[6] = (short)f2bf(v1.z); f[7] = (short)f2bf(v1.w);
            ea[ks] = f;
        }

        // MLP1: hid = relu(e W1 + b1) -> hF in A-frag layout (same-wave RAW).
#pragma unroll
        for (int nt = 0; nt < 8; ++nt) {
            const float bv = b1[16 * nt + c];
            f32x4 acc = {bv, bv, bv, bv};
#pragma unroll
            for (int ks = 0; ks < 2; ++ks) {
                const bf16x8 bf = *(const bf16x8*)&W1F[((ks * 8 + nt) * 64 + lane) * 8];
                acc = __builtin_amdgcn_mfma_f32_16x16x32_bf16(ea[ks], bf, acc, 0, 0, 0);
            }
            const int o   = 16 * nt + c;          // k2 index for MLP2
            const int ks2 = o >> 5;
            const int l4  = ((o >> 3) & 3) << 4;
            const int i   = o & 7;
#pragma unroll
            for (int r = 0; r < 4; ++r) {
                const float hv = fmaxf(acc[r], 0.f);
                hF[((w * 4 + ks2) * 64 + l4 + g * 4 + r) * 8 + i] = f2bf(hv);
            }
        }

        // MLP2: x = hid W2 + b2 + e
        bf16x8 ha[4];
#pragma unroll
        for (int ks = 0; ks < 4; ++ks)
            ha[ks] = *(const bf16x8*)&hF[((w * 4 + ks) * 64 + lane) * 8];

        float xf[4][4];   // [nt][r]
#pragma unroll
        for (int nt = 0; nt < 4; ++nt) {
            const float bv = b2[16 * nt + c];
            f32x4 acc = {bv, bv, bv, bv};
#pragma unroll
            for (int ks = 0; ks < 4; ++ks) {
                const bf16x8 bf = *(const bf16x8*)&W2F[((ks * 4 + nt) * 64 + lane) * 8];
                acc = __builtin_amdgcn_mfma_f32_16x16x32_bf16(ha[ks], bf, acc, 0, 0, 0);
            }
#pragma unroll
            for (int r = 0; r < 4; ++r)
                xf[nt][r] = acc[r] + eR[(16 * w + g * 4 + r) * 68 + 16 * nt + c];
        }

        // LayerNorm in registers over the 16 lanes sharing g
        float s4[4] = {0, 0, 0, 0}, q4[4] = {0, 0, 0, 0};
#pragma unroll
        for (int nt = 0; nt < 4; ++nt)
#pragma unroll
            for (int r = 0; r < 4; ++r) {
                s4[r] += xf[nt][r];
                q4[r] = fmaf(xf[nt][r], xf[nt][r], q4[r]);
            }
#pragma unroll
        for (int m = 1; m < 16; m <<= 1)
#pragma unroll
            for (int r = 0; r < 4; ++r) {
                s4[r] += __shfl_xor(s4[r], m);
                q4[r] += __shfl_xor(q4[r], m);
            }
        float mu[4], rstd[4];
#pragma unroll
        for (int r = 0; r < 4; ++r) {
            mu[r] = s4[r] * (1.0f / 64.0f);
            const float var = q4[r] * (1.0f / 64.0f) - mu[r] * mu[r];
            rstd[r] = 1.0f / sqrtf(var + LN_EPS);
        }

        // normalize, bf16-round; hh over ROUNDED values; pack 4 rows ->
        // one ds_write_b64 per nt into hT.
        float hh[4] = {0, 0, 0, 0};
#pragma unroll
        for (int nt = 0; nt < 4; ++nt) {
            const int o = 16 * nt + c;
            const float gm = gamma[o], bt = beta[o];
            ushort4 pk4;
            u16* pp = (u16*)&pk4;
#pragma unroll
            for (int r = 0; r < 4; ++r) {
                const float ov = (xf[nt][r] - mu[r]) * rstd[r] * gm + bt;
                const u16 rb = f2bf(ov);
                const float qf = bf2f(rb);
                hh[r] = fmaf(qf, qf, hh[r]);
                u16 st = rb;
                if (s == 0 && w == 3 && g == 3 && r == 3) {  // token 2047
                    q_ws[b * 64 + o] = rb;   // export q
                    st = 0;                   // padded key sigma=0
                }
                pp[r] = st;
            }
            *(ushort4*)&hT[o * 72 + 16 * w + 4 * g] = pk4;
        }
#pragma unroll
        for (int m = 1; m < 16; m <<= 1)
#pragma unroll
            for (int r = 0; r < 4; ++r) hh[r] += __shfl_xor(hh[r], m);
        if (c == 0) {
#pragma unroll
            for (int r = 0; r < 4; ++r)
                invd_l[16 * w + g * 4 + r] = 1.0f / (hh[r] + D_EPS);
        }
    }
    __syncthreads();   // hT/invd finalized

    // ======================= Phase B: compose (MFMA, lockstep) ============
    {
        float* Gm = (float*)(smem + B_GM);              // shared (wave0-written)
        u16*   Bh = (u16*)(smem + B_BH);                // shared
        u16*   Bl = (u16*)(smem + B_BL);                // shared
        u16*   Sh = (u16*)(smem + B_SH) + w * 1152;     // per-wave S^T hi
        u16*   Sl = (u16*)(smem + B_SL) + w * 1152;     // per-wave S^T lo
        u32*   Zn = (u32*)(smem + B_ZN) + w * 320;      // per-wave
        u32*   Zv = (u32*)(smem + B_ZV) + w * 320;

        // init: S = I (wave w's column block), V = 0; S^T split to LDS
        f32x4 Sacc[4], Vacc[4];
#pragma unroll
        for (int mt = 0; mt < 4; ++mt) {
            ushort4 h4, l4;
            u16* hp = (u16*)&h4;
#pragma unroll
            for (int r = 0; r < 4; ++r) {
                const int m = 16 * mt + 4 * g + r;
                const float v = (m == 16 * w + c) ? 1.0f : 0.0f;
                Sacc[mt][r] = v;
                Vacc[mt][r] = 0.f;
                hp[r] = f2bf(v);
            }
            l4.x = 0; l4.y = 0; l4.z = 0; l4.w = 0;
            *(ushort4*)&Sh[c * 72 + 16 * mt + 4 * g] = h4;
            *(ushort4*)&Sl[c * 72 + 16 * mt + 4 * g] = l4;
        }

        // prologue: wave0 computes Gram for chunk 0 (hT read-only, strided)
        if (w == 0) {
            const int basep = 63;
            bf16x8 ka[2];
#pragma unroll
            for (int f = 0; f < 2; ++f) {
                bf16x8 kf;
#pragma unroll
                for (int i = 0; i < 8; ++i)
                    kf[i] = (short)hT[(f * 32 + g * 8 + i) * 72 + (basep - c)];
                ka[f] = kf;
            }
            f32x4 gacc = {0.f, 0.f, 0.f, 0.f};
            gacc = __builtin_amdgcn_mfma_f32_16x16x32_bf16(ka[0], ka[0], gacc, 0, 0, 0);
            gacc = __builtin_amdgcn_mfma_f32_16x16x32_bf16(ka[1], ka[1], gacc, 0, 0, 0);
            const float ivc = invd_l[basep - c];
#pragma unroll
            for (int r = 0; r < 4; ++r)
                Gm[(4 * g + r) * 17 + c] = gacc[r] * ivc;
        }

        for (int cc = 0; cc < CPS; ++cc) {
            const int base = 63 - 16 * cc;
            __syncthreads();   // B_a: Gm(cc) visible; prev-chunk Bh reads done

            // ---- fwd-sub, distributed: wave w handles columns 16w+c ----
            if (g == 0) {
                const int m = 16 * w + c;
                const u16* hp = &hT[m * 72 + base - 15];
                const ushort4 k0 = *(const ushort4*)&hp[0];
                const ushort4 k1 = *(const ushort4*)&hp[4];
                const ushort4 k2 = *(const ushort4*)&hp[8];
                const ushort4 k3 = *(const ushort4*)&hp[12];
                const u16 kv[16] = {k0.x, k0.y, k0.z, k0.w, k1.x, k1.y, k1.z, k1.w,
                                    k2.x, k2.y, k2.z, k2.w, k3.x, k3.y, k3.z, k3.w};
                float Breg[16];
#pragma unroll
                for (int i = 0; i < 16; ++i) {
                    float acc = bf2f(kv[15 - i]);   // hT idx j -> slot i=15-j
#pragma unroll
                    for (int j = 0; j < 16; ++j)
                        if (j < i) acc = fmaf(-Gm[i * 17 + j], Breg[j], acc);
                    Breg[i] = acc;
                }
#pragma unroll
                for (int i = 0; i < 16; ++i) {
                    const u16 hb = f2bf(Breg[i]);
                    Bh[i * 72 + m] = hb;
                    Bl[i * 72 + m] = f2bf(Breg[i] - bf2f(hb));
                }
            }
            __syncthreads();   // B_b: Bh/Bl visible

            // ---- Z = B * S (split-bf16, 6 MFMAs; own column block) ----
            const bf16x8 abh0 = *(const bf16x8*)&Bh[c * 72 +  0 + g * 8];
            const bf16x8 abh1 = *(const bf16x8*)&Bh[c * 72 + 32 + g * 8];
            const bf16x8 abl0 = *(const bf16x8*)&Bl[c * 72 +  0 + g * 8];
            const bf16x8 abl1 = *(const bf16x8*)&Bl[c * 72 + 32 + g * 8];
            const bf16x8 sh0  = *(const bf16x8*)&Sh[c * 72 +  0 + g * 8];
            const bf16x8 sh1  = *(const bf16x8*)&Sh[c * 72 + 32 + g * 8];
            const bf16x8 sl0  = *(const bf16x8*)&Sl[c * 72 +  0 + g * 8];
            const bf16x8 sl1  = *(const bf16x8*)&Sl[c * 72 + 32 + g * 8];
            f32x4 zacc = {0.f, 0.f, 0.f, 0.f};
            zacc = __builtin_amdgcn_mfma_f32_16x16x32_bf16(abh0, sh0, zacc, 0, 0, 0);
            zacc = __builtin_amdgcn_mfma_f32_16x16x32_bf16(abh1, sh1, zacc, 0, 0, 0);
            zacc = __builtin_amdgcn_mfma_f32_16x16x32_bf16(abh0, sl0, zacc, 0, 0, 0);
            zacc = __builtin_amdgcn_mfma_f32_16x16x32_bf16(abh1, sl1, zacc, 0, 0, 0);
            zacc = __builtin_amdgcn_mfma_f32_16x16x32_bf16(abl0, sh0, zacc, 0, 0, 0);
            zacc = __builtin_amdgcn_mfma_f32_16x16x32_bf16(abl1, sh1, zacc, 0, 0, 0);

            // ---- scale by invd, split, pack (hi<<16)|lo ----
            uint4 znp, zvp;
            u32* znpp = (u32*)&znp;
            u32* zvpp = (u32*)&zvp;
#pragma unroll
            for (int r = 0; r < 4; ++r) {
                const int j = 4 * g + r;
                const float iv = invd_l[base - j];
                const float z  = zacc[r];
                const float zt = -z * iv;
                const u16 nh = f2bf(zt);
                const u16 nl = f2bf(zt - bf2f(nh));
                znpp[r] = ((u32)nh << 16) | (u32)nl;
                const u16 vh = f2bf(z);
                const u16 vl = f2bf(z - bf2f(vh));
                zvpp[r] = ((u32)vh << 16) | (u32)vl;
            }
            *(uint4*)&Zn[c * 20 + 4 * g] = znp;
            *(uint4*)&Zv[c * 20 + 4 * g] = zvp;

            // ---- read back as B-frags (rows j0..j0+7; hi for g<2, lo else) ----
            const int j0 = (g & 1) * 8;
            const uint4 za0 = *(const uint4*)&Zn[c * 20 + j0];
            const uint4 za1 = *(const uint4*)&Zn[c * 20 + j0 + 4];
            const uint4 zb0 = *(const uint4*)&Zv[c * 20 + j0];
            const uint4 zb1 = *(const uint4*)&Zv[c * 20 + j0 + 4];
            bf16x8 znf, zvf;
            {
                const u32 zn8[8] = {za0.x, za0.y, za0.z, za0.w, za1.x, za1.y, za1.z, za1.w};
                const u32 zv8[8] = {zb0.x, zb0.y, zb0.z, zb0.w, zb1.x, zb1.y, zb1.z, zb1.w};
                const bool hi = (g < 2);
#pragma unroll
                for (int i8 = 0; i8 < 8; ++i8) {
                    znf[i8] = (short)(hi ? (zn8[i8] >> 16) : (zn8[i8] & 0xFFFFu));
                    zvf[i8] = (short)(hi ? (zv8[i8] >> 16) : (zv8[i8] & 0xFFFFu));
                }
            }

            // ---- S/V update: A-frag K^T via vector hT reads ----
#pragma unroll
            for (int mt = 0; mt < 4; ++mt) {
                const u16* kp = &hT[(16 * mt + c) * 72 + base - j0 - 7];
                const ushort4 ta = *(const ushort4*)&kp[0];
                const ushort4 tb = *(const ushort4*)&kp[4];
                const u16 kvv[8] = {ta.x, ta.y, ta.z, ta.w, tb.x, tb.y, tb.z, tb.w};
                bf16x8 kaf;
#pragma unroll
                for (int i8 = 0; i8 < 8; ++i8)
                    kaf[i8] = (short)kvv[7 - i8];   // hT idx j -> i8 = 7-j
                Sacc[mt] = __builtin_amdgcn_mfma_f32_16x16x32_bf16(kaf, znf, Sacc[mt], 0, 0, 0);
                Vacc[mt] = __builtin_amdgcn_mfma_f32_16x16x32_bf16(kaf, zvf, Vacc[mt], 0, 0, 0);
            }
            // refresh S^T split in LDS for next chunk (same-wave only)
            if (cc < CPS - 1) {
#pragma unroll
                for (int mt = 0; mt < 4; ++mt) {
                    ushort4 h4, l4;
                    u16* hp = (u16*)&h4;
                    u16* lp = (u16*)&l4;
#pragma unroll
                    for (int r = 0; r < 4; ++r) {
                        const float sv = Sacc[mt][r];
                        const u16 hb = f2bf(sv);
                        hp[r] = hb;
                        lp[r] = f2bf(sv - bf2f(hb));
                    }
                    *(ushort4*)&Sh[c * 72 + 16 * mt + 4 * g] = h4;
                    *(ushort4*)&Sl[c * 72 + 16 * mt + 4 * g] = l4;
                }
            }
            // ---- pipeline: wave0 computes Gram for chunk cc+1 (from hT) ----
            if (w == 0 && cc + 1 < CPS) {
                const int basep = base - 16;
                bf16x8 ka[2];
#pragma unroll
                for (int f = 0; f < 2; ++f) {
                    bf16x8 kf;
#pragma unroll
                    for (int i = 0; i < 8; ++i)
                        kf[i] = (short)hT[(f * 32 + g * 8 + i) * 72 + (basep - c)];
                    ka[f] = kf;
                }
                f32x4 gacc = {0.f, 0.f, 0.f, 0.f};
                gacc = __builtin_amdgcn_mfma_f32_16x16x32_bf16(ka[0], ka[0], gacc, 0, 0, 0);
                gacc = __builtin_amdgcn_mfma_f32_16x16x32_bf16(ka[1], ka[1], gacc, 0, 0, 0);
                const float ivc = invd_l[basep - c];
#pragma unroll
                for (int r = 0; r < 4; ++r)
                    Gm[(4 * g + r) * 17 + c] = gacc[r] * ivc;
            }
        }

        // writeback: pk[j*64+i] = pack(bf16 S[i][j], bf16 V[i][j])
        u32* pk = PK + ((size_t)(b * NSEG + s) << 12);
#pragma unroll
        for (int mt = 0; mt < 4; ++mt) {
            uint4 o;
            u32* op = (u32*)&o;
#pragma unroll
            for (int r = 0; r < 4; ++r)
                op[r] = ((u32)f2bf(Sacc[mt][r]) << 16) | (u32)f2bf(Vacc[mt][r]);
            *(uint4*)&pk[(16 * w + c) * 64 + 16 * mt + 4 * g] = o;
        }
    }
}

// ---------------------------------------------------------------------------
// Kernel B: serial segment pass + output projection (R4-exact).
// ---------------------------------------------------------------------------
__global__ __launch_bounds__(256, 1) void final_kernel(
    const u16* __restrict__ q_ws, const u32* __restrict__ PK,
    const float* __restrict__ Wr, const float* __restrict__ br,
    const float* __restrict__ Wo, const float* __restrict__ bo,
    float* __restrict__ out)
{
    const int b    = blockIdx.x;
    const int t    = threadIdx.x;
    const int lane = t & 63;
    const int p    = t >> 6;         // wave id = j-slice

    __shared__ float psum[4][72];
    __shared__ float rl[64];
    __shared__ float cs[64], rs[64];

    rl[lane] = bf2f(q_ws[b * 64 + lane]);

    float ctxp = 0.f;
    u32 cur[16], nxt[16];
    {
        const u32* pk0 = PK + ((size_t)(b * NSEG + 0) << 12);
#pragma unroll
        for (int jj = 0; jj < 16; ++jj)
            cur[jj] = pk0[(p * 16 + jj) * 64 + lane];
    }
    __syncthreads();

    for (int s = 0; s < NSEG; ++s) {
        const int sn = (s + 1 < NSEG) ? s + 1 : s;
        const u32* pkn = PK + ((size_t)(b * NSEG + sn) << 12);
#pragma unroll
        for (int jj = 0; jj < 16; ++jj)
            nxt[jj] = pkn[(p * 16 + jj) * 64 + lane];

        float accr = 0.f;
#pragma unroll
        for (int jj = 0; jj < 16; ++jj) {
            const u32 pv = cur[jj];
            const float Sv = __uint_as_float(pv & 0xFFFF0000u);
            const float Vv = __uint_as_float(pv << 16);
            const float rj = rl[p * 16 + jj];
            accr = fmaf(Sv, rj, accr);
            ctxp = fmaf(Vv, rj, ctxp);
        }
        psum[p][lane] = accr;
        __syncthreads();
        const float rn = (psum[0][lane] + psum[1][lane]) + (psum[2][lane] + psum[3][lane]);
        __syncthreads();
        rl[lane] = rn;

#pragma unroll
        for (int jj = 0; jj < 16; ++jj) cur[jj] = nxt[jj];
    }

    psum[p][lane] = ctxp;
    __syncthreads();
    if (t < 64)
        cs[t] = (psum[0][t] + psum[1][t]) + (psum[2][t] + psum[3][t]);
    __syncthreads();

    float rv = (p == 0) ? br[lane] : 0.f;
#pragma unroll
    for (int i = 0; i < 16; ++i)
        rv = fmaf(cs[p * 16 + i], Wr[(p * 16 + i) * HDIM + lane], rv);
    psum[p][lane] = rv;
    __syncthreads();
    if (t < 64)
        rs[t] = (psum[0][t] + psum[1][t]) + (psum[2][t] + psum[3][t]);
    __syncthreads();

    float ov = (p == 0) ? bo[lane] : 0.f;
#pragma unroll
    for (int i = 0; i < 16; ++i)
        ov = fmaf(rs[p * 16 + i], Wo[(p * 16 + i) * HDIM + lane], ov);
    psum[p][lane] = ov;
    __syncthreads();
    if (t < 64)
        out[(size_t)b * HDIM + t] = (psum[0][t] + psum[1][t]) + (psum[2][t] + psum[3][t]);
}

// ---------------------------------------------------------------------------
extern "C" void kernel_launch(void* const* d_in, const int* in_sizes, int n_in,
                              void* d_out, int out_size, void* d_ws, size_t ws_size,
                              hipStream_t stream)
{
    const int*   seq   = (const int*)  d_in[0];
    const float* embed = (const float*)d_in[1];
    const float* W1    = (const float*)d_in[2];
    const float* b1    = (const float*)d_in[3];
    const float* W2    = (const float*)d_in[4];
    const float* b2    = (const float*)d_in[5];
    const float* gamma = (const float*)d_in[6];
    const float* beta  = (const float*)d_in[7];
    const float* Wr    = (const float*)d_in[8];
    const float* br    = (const float*)d_in[9];
    const float* Wo    = (const float*)d_in[10];
    const float* bo    = (const float*)d_in[11];

    u32* pk_ws = (u32*)d_ws;                                  // 8 MB (16*32*4096 u32)
    u16* q_ws  = (u16*)(pk_ws + (size_t)BATCH * NSEG * 4096); // 2 KB
    u16* W1F   = q_ws + (size_t)BATCH * 64;                   // 16 KB (8192 bf16)
    u16* W2F   = W1F + 64 * 128;                              // 16 KB
    float* outp = (float*)d_out;

    hipLaunchKernelGGL(prep_w_kernel, dim3(8), dim3(256), 0, stream,
                       W1, W2, W1F, W2F);
    hipLaunchKernelGGL(fused_pc_kernel, dim3(BATCH * NSEG), dim3(256), 0, stream,
                       seq, embed, W1F, b1, W2F, b2, gamma, beta, pk_ws, q_ws);
    hipLaunchKernelGGL(final_kernel, dim3(BATCH), dim3(256), 0, stream,
                       q_ws, pk_ws, Wr, br, Wo, bo, outp);
}